// Round 4
// baseline (820.475 us; speedup 1.0000x reference)
//
#include <hip/hip_runtime.h>

#define NEG_SLOPE 0.2f

__device__ __forceinline__ float lrelu(float x) { return x > 0.f ? x : NEG_SLOPE * x; }

// order-preserving float->uint encoding for atomic max
__device__ __forceinline__ unsigned fenc(float x) {
    unsigned u = __float_as_uint(x);
    return (u & 0x80000000u) ? ~u : (u | 0x80000000u);
}
__device__ __forceinline__ float fdec(unsigned u) {
    return (u & 0x80000000u) ? __uint_as_float(u ^ 0x80000000u) : __uint_as_float(~u);
}

// ---------------------------------------------------------------------------
// K1: h = X @ W (register-tiled) + per-(node,head) attention logits.
// QMAJOR=true: store H in quadrant-major layout Hq[8][n][16]
//   (slab q = features [q*16, q*16+16) of the flat 128-wide row)
// ---------------------------------------------------------------------------
template<int K, int OUT, int F, bool QMAJOR>
__global__ __launch_bounds__(256) void gemm_logits(
    const float* __restrict__ X, const float* __restrict__ W,
    const float* __restrict__ a_s, const float* __restrict__ a_d,
    float* __restrict__ Hout, float* __restrict__ als, float* __restrict__ ald,
    int n)
{
    constexpr int TX = OUT / 4;
    constexpr int TY = 256 / TX;
    constexpr int MR = 8;
    constexpr int BM = TY * MR;
    constexpr int KC = 32;

    __shared__ __align__(16) float Xs[BM][KC];
    __shared__ __align__(16) float Ws[KC][OUT];

    const int tx = (int)threadIdx.x % TX;
    const int ty = (int)threadIdx.x / TX;
    const int r0 = blockIdx.x * BM;

    float4 acc[MR];
#pragma unroll
    for (int m = 0; m < MR; ++m) acc[m] = make_float4(0.f, 0.f, 0.f, 0.f);

    for (int kc = 0; kc < K; kc += KC) {
        __syncthreads();
        constexpr int XV = BM * KC / 4;
#pragma unroll
        for (int i = threadIdx.x; i < XV; i += 256) {
            int f = i * 4;
            int r = f / KC, k = f % KC;
            int gr = r0 + r;
            float4 v = make_float4(0.f, 0.f, 0.f, 0.f);
            if (gr < n) v = *(const float4*)(X + (size_t)gr * K + kc + k);
            *(float4*)(&Xs[r][k]) = v;
        }
        constexpr int WV = KC * OUT / 4;
#pragma unroll
        for (int i = threadIdx.x; i < WV; i += 256) {
            int f = i * 4;
            int k = f / OUT, c = f % OUT;
            *(float4*)(&Ws[k][c]) = *(const float4*)(W + (size_t)(kc + k) * OUT + c);
        }
        __syncthreads();

#pragma unroll
        for (int k4 = 0; k4 < KC; k4 += 4) {
            float4 xv[MR];
#pragma unroll
            for (int m = 0; m < MR; ++m)
                xv[m] = *(const float4*)(&Xs[ty * MR + m][k4]);
#pragma unroll
            for (int kk = 0; kk < 4; ++kk) {
                float4 wv = *(const float4*)(&Ws[k4 + kk][tx * 4]);
#pragma unroll
                for (int m = 0; m < MR; ++m) {
                    float xm = kk == 0 ? xv[m].x : kk == 1 ? xv[m].y : kk == 2 ? xv[m].z : xv[m].w;
                    acc[m].x = fmaf(xm, wv.x, acc[m].x);
                    acc[m].y = fmaf(xm, wv.y, acc[m].y);
                    acc[m].z = fmaf(xm, wv.z, acc[m].z);
                    acc[m].w = fmaf(xm, wv.w, acc[m].w);
                }
            }
        }
    }

    const float4 asv = *(const float4*)(a_s + tx * 4);
    const float4 adv = *(const float4*)(a_d + tx * 4);
    constexpr int UH = F / 4;
    const int head = tx / UH;
#pragma unroll
    for (int m = 0; m < MR; ++m) {
        int gr = r0 + ty * MR + m;
        float ps = acc[m].x * asv.x + acc[m].y * asv.y + acc[m].z * asv.z + acc[m].w * asv.w;
        float pd = acc[m].x * adv.x + acc[m].y * adv.y + acc[m].z * adv.z + acc[m].w * adv.w;
#pragma unroll
        for (int off = UH / 2; off > 0; off >>= 1) {
            ps += __shfl_xor(ps, off, 64);
            pd += __shfl_xor(pd, off, 64);
        }
        if (gr < n) {
            if (QMAJOR) {
                int qg = tx / 4;           // feature quadrant (0..7 for OUT=128)
                int off16 = (tx & 3) * 4;
                *(float4*)(Hout + ((size_t)qg * n + gr) * 16 + off16) = acc[m];
            } else {
                *(float4*)(Hout + (size_t)gr * OUT + tx * 4) = acc[m];
            }
            if ((tx % UH) == 0) {
                als[gr * 2 + head] = ps;
                ald[gr * 2 + head] = pd;
            }
        }
    }
}

// ---------------------------------------------------------------------------
// CSR build (edges identical for all 3 layers -> build once per call)
// ---------------------------------------------------------------------------
__global__ __launch_bounds__(256) void k_zero_int(int* __restrict__ p, int n) {
    int i = blockIdx.x * 256 + threadIdx.x;
    if (i < n) p[i] = 0;
}

__global__ __launch_bounds__(256) void k_hist(const int* __restrict__ dst,
                                              int* __restrict__ deg, int E) {
    int e = blockIdx.x * 256 + threadIdx.x;
    if (e < E) atomicAdd(&deg[dst[e]], 1);
}

__global__ __launch_bounds__(1024) void k_scan(const int* __restrict__ deg,
                                               int* __restrict__ rowptr,
                                               int* __restrict__ cursor, int n) {
    __shared__ int sm[1024];
    int t = threadIdx.x;
    int chunk = (n + 1023) / 1024;
    int b = t * chunk, e = min(n, b + chunk);
    int s = 0;
    for (int i = b; i < e; ++i) s += deg[i];
    sm[t] = s;
    __syncthreads();
    for (int off = 1; off < 1024; off <<= 1) {
        int v = (t >= off) ? sm[t - off] : 0;
        __syncthreads();
        sm[t] += v;
        __syncthreads();
    }
    int run = (t == 0) ? 0 : sm[t - 1];
    for (int i = b; i < e; ++i) {
        rowptr[i] = run;
        cursor[i] = run;
        run += deg[i];
    }
    if (t == 1023) rowptr[n] = sm[1023];
}

__global__ __launch_bounds__(256) void k_scatter(const int* __restrict__ src,
                                                 const int* __restrict__ dst,
                                                 int* __restrict__ cursor,
                                                 int* __restrict__ esorted,
                                                 int* __restrict__ dsorted, int E) {
    int e = blockIdx.x * 256 + threadIdx.x;
    if (e >= E) return;
    int d = dst[e];
    int p = atomicAdd(&cursor[d], 1);
    esorted[p] = src[e];
    dsorted[p] = d;
}

// ---------------------------------------------------------------------------
// A1: init per-(node,head) max with the self-loop source logit
// ---------------------------------------------------------------------------
__global__ __launch_bounds__(256) void node_init_max(
    const float* __restrict__ als, unsigned* __restrict__ maxb, int n2)
{
    int i = blockIdx.x * 256 + threadIdx.x;
    if (i < n2) maxb[i] = fenc(als[i]);
}

// ---------------------------------------------------------------------------
// A2: edge-parallel atomic max of al_s[src] into maxb[dst] (both heads)
// ---------------------------------------------------------------------------
__global__ __launch_bounds__(256) void edge_max(
    const int* __restrict__ src, const int* __restrict__ dst,
    const float* __restrict__ als, unsigned* __restrict__ maxb, int E)
{
    int e = blockIdx.x * 256 + threadIdx.x;
    if (e >= E) return;
    int s = src[e], d = dst[e];
    atomicMax(&maxb[d * 2 + 0], fenc(als[s * 2 + 0]));
    atomicMax(&maxb[d * 2 + 1], fenc(als[s * 2 + 1]));
}

// ---------------------------------------------------------------------------
// A3: per (node,head): m = lrelu(max+al_d); den init with self-loop weight
// ---------------------------------------------------------------------------
__global__ __launch_bounds__(256) void node_prep(
    const float* __restrict__ als, const float* __restrict__ ald,
    const unsigned* __restrict__ maxb, float* __restrict__ mbuf,
    float* __restrict__ den, int n2)
{
    int i = blockIdx.x * 256 + threadIdx.x;
    if (i >= n2) return;
    float a_ld = ald[i];
    float m = lrelu(fdec(maxb[i]) + a_ld);
    mbuf[i] = m;
    den[i] = expf(lrelu(als[i] + a_ld) - m);
}

// ---------------------------------------------------------------------------
// A4: per sorted edge: w = exp(lrelu(als[s]+ald[d]) - m[d]) for both heads;
//     store dst-sorted into wbuf[h][p]; den[d,h] += w
// ---------------------------------------------------------------------------
__global__ __launch_bounds__(256) void edge_weights(
    const int* __restrict__ esorted, const int* __restrict__ dsorted,
    const float* __restrict__ als, const float* __restrict__ ald,
    const float* __restrict__ mbuf, float* __restrict__ wbuf,
    float* __restrict__ den, int E)
{
    int p = blockIdx.x * 256 + threadIdx.x;
    if (p >= E) return;
    int s = esorted[p], d = dsorted[p];
#pragma unroll
    for (int h = 0; h < 2; ++h) {
        float w = expf(lrelu(als[s * 2 + h] + ald[d * 2 + h]) - mbuf[d * 2 + h]);
        wbuf[(size_t)h * E + p] = w;
        atomicAdd(&den[d * 2 + h], w);
    }
}

// ---------------------------------------------------------------------------
// C: quadrant-sliced gather-accumulate.
// blockIdx%8 = quadrant (XCD steering: each XCD caches one 3.2 MB H slab).
// 16-lane group per node; reads esorted + wbuf sequentially; epilogue
// folds 1/den, bias, relu. out is standard [node][128] layout.
// ---------------------------------------------------------------------------
__global__ __launch_bounds__(256) void gat_gather_quad(
    const int* __restrict__ rowptr, const int* __restrict__ esrc,
    const float* __restrict__ wbuf, const float* __restrict__ als,
    const float* __restrict__ ald, const float* __restrict__ mbuf,
    const float* __restrict__ den, const float* __restrict__ Hq,
    const float* __restrict__ bias, float* __restrict__ out, int N, int E)
{
    const int qq = blockIdx.x & 7;          // feature quadrant 0..7
    const int nodeblk = blockIdx.x >> 3;
    const int node = nodeblk * 16 + ((int)threadIdx.x >> 4);
    const int lane = (int)threadIdx.x & 15;
    if (node >= N) return;
    const int head = qq >> 2;
    const int g = node * 2 + head;

    const float* __restrict__ slab = Hq + (size_t)qq * N * 16;
    const float* __restrict__ wrow = wbuf + (size_t)head * E;

    float wself = expf(lrelu(als[g] + ald[g]) - mbuf[g]);
    float acc = wself * slab[(size_t)node * 16 + lane];

    int p = rowptr[node];
    const int end = rowptr[node + 1];
    for (; p + 3 < end; p += 4) {
        int s0 = esrc[p], s1 = esrc[p + 1], s2 = esrc[p + 2], s3 = esrc[p + 3];
        float w0 = wrow[p], w1 = wrow[p + 1], w2 = wrow[p + 2], w3 = wrow[p + 3];
        float h0 = slab[(size_t)s0 * 16 + lane];
        float h1 = slab[(size_t)s1 * 16 + lane];
        float h2 = slab[(size_t)s2 * 16 + lane];
        float h3 = slab[(size_t)s3 * 16 + lane];
        acc = fmaf(w0, h0, acc);
        acc = fmaf(w1, h1, acc);
        acc = fmaf(w2, h2, acc);
        acc = fmaf(w3, h3, acc);
    }
    for (; p < end; ++p)
        acc = fmaf(wrow[p], slab[(size_t)esrc[p] * 16 + lane], acc);

    float rden = 1.f / (den[g] + 1e-16f);
    float v = acc * rden + bias[qq * 16 + lane];
    out[(size_t)node * 128 + qq * 16 + lane] = v > 0.f ? v : 0.f;
}

// ---------------------------------------------------------------------------
// layer-3 aggregate (F=16, standard H layout) — unchanged from R3
// ---------------------------------------------------------------------------
template<int F, bool RELU>
__global__ __launch_bounds__(256) void gat_aggregate(
    const int* __restrict__ rowptr, const int* __restrict__ esrc,
    const float* __restrict__ als, const float* __restrict__ ald,
    const float* __restrict__ H, const float* __restrict__ bias,
    float* __restrict__ out, float* __restrict__ denom, int n2)
{
    int g = blockIdx.x * (256 / F) + (int)threadIdx.x / F;
    int lane = (int)threadIdx.x % F;
    if (g >= n2) return;
    int node = g >> 1, head = g & 1;

    float alsd = als[g], aldd = ald[g];
    int beg = rowptr[node], end = rowptr[node + 1];

    float mx = alsd;
    for (int i = beg + lane; i < end; i += F)
        mx = fmaxf(mx, als[esrc[i] * 2 + head]);
#pragma unroll
    for (int off = F / 2; off > 0; off >>= 1)
        mx = fmaxf(mx, __shfl_xor(mx, off, 64));
    float m = lrelu(mx + aldd);

    float wself = expf(lrelu(alsd + aldd) - m);
    float acc = wself * H[(size_t)g * F + lane];
    float den = 0.f;

    int wl = (int)threadIdx.x & 63;
    int gb = wl & ~(F - 1);

    for (int base = beg; base < end; base += F) {
        int cnt = min(F, end - base);
        int s = 0;
        float w = 0.f;
        if (lane < cnt) {
            s = esrc[base + lane];
            w = expf(lrelu(als[s * 2 + head] + aldd) - m);
        }
        den += w;
        for (int i = 0; i < cnt; ++i) {
            int si = __shfl(s, gb + i, 64);
            float wi = __shfl(w, gb + i, 64);
            acc = fmaf(wi, H[((size_t)si * 2 + head) * F + lane], acc);
        }
    }
#pragma unroll
    for (int off = F / 2; off > 0; off >>= 1)
        den += __shfl_xor(den, off, 64);
    den += wself;

    if (RELU) {
        float v = acc / (den + 1e-16f) + bias[head * F + lane];
        out[(size_t)g * F + lane] = v > 0.f ? v : 0.f;
    } else {
        out[(size_t)g * F + lane] = acc;
        if (lane == 0) denom[g] = den;
    }
}

// ---------------------------------------------------------------------------
// K6b: layer 3 finalize: mean over heads + b3, softmax over 16 classes
// ---------------------------------------------------------------------------
__global__ __launch_bounds__(256) void finalize3(
    const float* __restrict__ acc, const float* __restrict__ denom,
    const float* __restrict__ b, float* __restrict__ out, int n)
{
    int node = blockIdx.x * 16 + (int)threadIdx.x / 16;
    int f = (int)threadIdx.x % 16;
    if (node >= n) return;
    float v0 = acc[(size_t)node * 32 + f]      / (denom[node * 2 + 0] + 1e-16f);
    float v1 = acc[(size_t)node * 32 + 16 + f] / (denom[node * 2 + 1] + 1e-16f);
    float v = 0.5f * (v0 + v1) + b[f];
    float mx = v;
#pragma unroll
    for (int off = 8; off > 0; off >>= 1) mx = fmaxf(mx, __shfl_xor(mx, off, 64));
    float ex = expf(v - mx);
    float sum = ex;
#pragma unroll
    for (int off = 8; off > 0; off >>= 1) sum += __shfl_xor(sum, off, 64);
    out[(size_t)node * 16 + f] = ex / sum;
}

// ---------------------------------------------------------------------------
extern "C" void kernel_launch(void* const* d_in, const int* in_sizes, int n_in,
                              void* d_out, int out_size, void* d_ws, size_t ws_size,
                              hipStream_t stream)
{
    const float* feat = (const float*)d_in[0];
    const int*   ei   = (const int*)d_in[1];
    const float* W1 = (const float*)d_in[2];
    const float* a1s = (const float*)d_in[3];
    const float* a1d = (const float*)d_in[4];
    const float* b1 = (const float*)d_in[5];
    const float* W2 = (const float*)d_in[6];
    const float* a2s = (const float*)d_in[7];
    const float* a2d = (const float*)d_in[8];
    const float* b2 = (const float*)d_in[9];
    const float* W3 = (const float*)d_in[10];
    const float* a3s = (const float*)d_in[11];
    const float* a3d = (const float*)d_in[12];
    const float* b3 = (const float*)d_in[13];

    const int N = in_sizes[0] / 64;
    const int E = in_sizes[1] / 2;
    const int* src = ei;
    const int* dst = ei + E;
    const int n2 = N * 2;

    // workspace layout
    float* bufA  = (float*)d_ws;                    // N*128 (H / Hq slabs)
    float* bufB  = bufA + (size_t)N * 128;          // N*128 (x / acc)
    float* als   = bufB + (size_t)N * 128;          // n2
    float* ald   = als + (size_t)n2;                // n2
    float* mbuf  = ald + (size_t)n2;                // n2
    float* den   = mbuf + (size_t)n2;               // n2
    float* wbuf  = den + (size_t)n2;                // 2*E
    unsigned* maxb = (unsigned*)(wbuf + (size_t)2 * E);  // n2
    int* deg     = (int*)(maxb + (size_t)n2);       // N
    int* rowptr  = deg + N;                         // N+1
    int* cursor  = rowptr + (N + 1);                // N
    int* esorted = cursor + N;                      // E
    int* dsorted = esorted + E;                     // E

    dim3 blk(256);
    const int gE = (E + 255) / 256;
    const int gN2 = (n2 + 255) / 256;
    const int gC = 8 * ((N + 15) / 16);

    // --- build CSR by dst (once; shared by all 3 layers) ---
    k_zero_int<<<(N + 255) / 256, blk, 0, stream>>>(deg, N);
    k_hist<<<gE, blk, 0, stream>>>(dst, deg, E);
    k_scan<<<1, 1024, 0, stream>>>(deg, rowptr, cursor, N);
    k_scatter<<<gE, blk, 0, stream>>>(src, dst, cursor, esorted, dsorted, E);

    // --- layer 1 (K=64, OUT=128) ---
    gemm_logits<64, 128, 64, true><<<(N + 63) / 64, blk, 0, stream>>>(feat, W1, a1s, a1d, bufA, als, ald, N);
    node_init_max<<<gN2, blk, 0, stream>>>(als, maxb, n2);
    edge_max<<<gE, blk, 0, stream>>>(src, dst, als, maxb, E);
    node_prep<<<gN2, blk, 0, stream>>>(als, ald, maxb, mbuf, den, n2);
    edge_weights<<<gE, blk, 0, stream>>>(esorted, dsorted, als, ald, mbuf, wbuf, den, E);
    gat_gather_quad<<<gC, blk, 0, stream>>>(rowptr, esorted, wbuf, als, ald, mbuf, den, bufA, b1, bufB, N, E);

    // --- layer 2 (K=128, OUT=128) ---
    gemm_logits<128, 128, 64, true><<<(N + 63) / 64, blk, 0, stream>>>(bufB, W2, a2s, a2d, bufA, als, ald, N);
    node_init_max<<<gN2, blk, 0, stream>>>(als, maxb, n2);
    edge_max<<<gE, blk, 0, stream>>>(src, dst, als, maxb, E);
    node_prep<<<gN2, blk, 0, stream>>>(als, ald, maxb, mbuf, den, n2);
    edge_weights<<<gE, blk, 0, stream>>>(esorted, dsorted, als, ald, mbuf, wbuf, den, E);
    gat_gather_quad<<<gC, blk, 0, stream>>>(rowptr, esorted, wbuf, als, ald, mbuf, den, bufA, b2, bufB, N, E);

    // --- layer 3 (K=128, OUT=32, F=16) ---
    gemm_logits<128, 32, 16, false><<<(N + 255) / 256, blk, 0, stream>>>(bufB, W3, a3s, a3d, bufA, als, ald, N);
    gat_aggregate<16, false><<<(n2 + 15) / 16, blk, 0, stream>>>(
        rowptr, esorted, als, ald, bufA, nullptr, bufB, den, n2);
    finalize3<<<(N + 15) / 16, blk, 0, stream>>>(bufB, den, b3, (float*)d_out, N);
}

// Round 5
// 364.089 us; speedup vs baseline: 2.2535x; 2.2535x over previous
//
#include <hip/hip_runtime.h>

#define NEG_SLOPE 0.2f

__device__ __forceinline__ float lrelu(float x) { return x > 0.f ? x : NEG_SLOPE * x; }

// ---------------------------------------------------------------------------
// K1: h = X @ W (register-tiled) + per-(node,head) attention logits.
// 256 threads = TX x TY; thread computes MR=8 rows x 4 cols (float4 acc).
// ---------------------------------------------------------------------------
template<int K, int OUT, int F>
__global__ __launch_bounds__(256) void gemm_logits(
    const float* __restrict__ X, const float* __restrict__ W,
    const float* __restrict__ a_s, const float* __restrict__ a_d,
    float* __restrict__ Hout, float* __restrict__ als, float* __restrict__ ald,
    int n)
{
    constexpr int TX = OUT / 4;
    constexpr int TY = 256 / TX;
    constexpr int MR = 8;
    constexpr int BM = TY * MR;
    constexpr int KC = 32;

    __shared__ __align__(16) float Xs[BM][KC];
    __shared__ __align__(16) float Ws[KC][OUT];

    const int tx = (int)threadIdx.x % TX;
    const int ty = (int)threadIdx.x / TX;
    const int r0 = blockIdx.x * BM;

    float4 acc[MR];
#pragma unroll
    for (int m = 0; m < MR; ++m) acc[m] = make_float4(0.f, 0.f, 0.f, 0.f);

    for (int kc = 0; kc < K; kc += KC) {
        __syncthreads();
        constexpr int XV = BM * KC / 4;
#pragma unroll
        for (int i = threadIdx.x; i < XV; i += 256) {
            int f = i * 4;
            int r = f / KC, k = f % KC;
            int gr = r0 + r;
            float4 v = make_float4(0.f, 0.f, 0.f, 0.f);
            if (gr < n) v = *(const float4*)(X + (size_t)gr * K + kc + k);
            *(float4*)(&Xs[r][k]) = v;
        }
        constexpr int WV = KC * OUT / 4;
#pragma unroll
        for (int i = threadIdx.x; i < WV; i += 256) {
            int f = i * 4;
            int k = f / OUT, c = f % OUT;
            *(float4*)(&Ws[k][c]) = *(const float4*)(W + (size_t)(kc + k) * OUT + c);
        }
        __syncthreads();

#pragma unroll
        for (int k4 = 0; k4 < KC; k4 += 4) {
            float4 xv[MR];
#pragma unroll
            for (int m = 0; m < MR; ++m)
                xv[m] = *(const float4*)(&Xs[ty * MR + m][k4]);
#pragma unroll
            for (int kk = 0; kk < 4; ++kk) {
                float4 wv = *(const float4*)(&Ws[k4 + kk][tx * 4]);
#pragma unroll
                for (int m = 0; m < MR; ++m) {
                    float xm = kk == 0 ? xv[m].x : kk == 1 ? xv[m].y : kk == 2 ? xv[m].z : xv[m].w;
                    acc[m].x = fmaf(xm, wv.x, acc[m].x);
                    acc[m].y = fmaf(xm, wv.y, acc[m].y);
                    acc[m].z = fmaf(xm, wv.z, acc[m].z);
                    acc[m].w = fmaf(xm, wv.w, acc[m].w);
                }
            }
        }
    }

    const float4 asv = *(const float4*)(a_s + tx * 4);
    const float4 adv = *(const float4*)(a_d + tx * 4);
    constexpr int UH = F / 4;
    const int head = tx / UH;
#pragma unroll
    for (int m = 0; m < MR; ++m) {
        int gr = r0 + ty * MR + m;
        float ps = acc[m].x * asv.x + acc[m].y * asv.y + acc[m].z * asv.z + acc[m].w * asv.w;
        float pd = acc[m].x * adv.x + acc[m].y * adv.y + acc[m].z * adv.z + acc[m].w * adv.w;
#pragma unroll
        for (int off = UH / 2; off > 0; off >>= 1) {
            ps += __shfl_xor(ps, off, 64);
            pd += __shfl_xor(pd, off, 64);
        }
        if (gr < n) {
            *(float4*)(Hout + (size_t)gr * OUT + tx * 4) = acc[m];
            if ((tx % UH) == 0) {
                als[gr * 2 + head] = ps;
                ald[gr * 2 + head] = pd;
            }
        }
    }
}

// ---------------------------------------------------------------------------
// CSR build. Parallel 3-kernel scan (the old 1-block scan was 110 us).
// ---------------------------------------------------------------------------
#define SCAN_TILE 1024

__global__ __launch_bounds__(256) void k_zero_int(int* __restrict__ p, int n) {
    int i = blockIdx.x * 256 + threadIdx.x;
    if (i < n) p[i] = 0;
}

__global__ __launch_bounds__(256) void k_hist(const int* __restrict__ dst,
                                              int* __restrict__ deg, int E) {
    int e = blockIdx.x * 256 + threadIdx.x;
    if (e < E) atomicAdd(&deg[dst[e]], 1);
}

// per-tile totals (coalesced)
__global__ __launch_bounds__(256) void k_scan1(const int* __restrict__ deg,
                                               int* __restrict__ bsum, int N) {
    __shared__ int sm[256];
    int base = blockIdx.x * SCAN_TILE;
    int t = threadIdx.x;
    int s = 0;
#pragma unroll
    for (int j = 0; j < SCAN_TILE / 256; ++j) {
        int i = base + j * 256 + t;
        if (i < N) s += deg[i];
    }
    sm[t] = s;
    __syncthreads();
    for (int off = 128; off > 0; off >>= 1) {
        if (t < off) sm[t] += sm[t + off];
        __syncthreads();
    }
    if (t == 0) bsum[blockIdx.x] = sm[0];
}

// single-block scan of tile sums (nb <= 256)
__global__ __launch_bounds__(256) void k_scan2(const int* __restrict__ bsum,
                                               int* __restrict__ boff,
                                               int* __restrict__ rowptr,
                                               int nb, int N) {
    __shared__ int sm[256];
    int t = threadIdx.x;
    int v = (t < nb) ? bsum[t] : 0;
    sm[t] = v;
    __syncthreads();
    for (int off = 1; off < 256; off <<= 1) {
        int u = (t >= off) ? sm[t - off] : 0;
        __syncthreads();
        sm[t] += u;
        __syncthreads();
    }
    if (t < nb) boff[t] = sm[t] - v;
    if (t == 255) rowptr[N] = sm[255];
}

// per-tile local exclusive scan + offset; writes rowptr & cursor
__global__ __launch_bounds__(256) void k_scan3(const int* __restrict__ deg,
                                               const int* __restrict__ boff,
                                               int* __restrict__ rowptr,
                                               int* __restrict__ cursor, int N) {
    __shared__ int sm[256];
    int base = blockIdx.x * SCAN_TILE;
    int t = threadIdx.x;
    int i0 = base + t * 4;
    int d0 = 0, d1 = 0, d2 = 0, d3 = 0;
    if (i0 + 3 < N) {
        int4 v = *(const int4*)(deg + i0);
        d0 = v.x; d1 = v.y; d2 = v.z; d3 = v.w;
    } else {
        if (i0 + 0 < N) d0 = deg[i0 + 0];
        if (i0 + 1 < N) d1 = deg[i0 + 1];
        if (i0 + 2 < N) d2 = deg[i0 + 2];
        if (i0 + 3 < N) d3 = deg[i0 + 3];
    }
    int tsum = d0 + d1 + d2 + d3;
    sm[t] = tsum;
    __syncthreads();
    for (int off = 1; off < 256; off <<= 1) {
        int u = (t >= off) ? sm[t - off] : 0;
        __syncthreads();
        sm[t] += u;
        __syncthreads();
    }
    int run = boff[blockIdx.x] + sm[t] - tsum;
    if (i0 + 0 < N) { rowptr[i0 + 0] = run; cursor[i0 + 0] = run; run += d0; }
    if (i0 + 1 < N) { rowptr[i0 + 1] = run; cursor[i0 + 1] = run; run += d1; }
    if (i0 + 2 < N) { rowptr[i0 + 2] = run; cursor[i0 + 2] = run; run += d2; }
    if (i0 + 3 < N) { rowptr[i0 + 3] = run; cursor[i0 + 3] = run; run += d3; }
}

__global__ __launch_bounds__(256) void k_scatter(const int* __restrict__ src,
                                                 const int* __restrict__ dst,
                                                 int* __restrict__ cursor,
                                                 int* __restrict__ esorted, int E) {
    int e = blockIdx.x * 256 + threadIdx.x;
    if (e >= E) return;
    int p = atomicAdd(&cursor[dst[e]], 1);
    esorted[p] = src[e];
}

// ---------------------------------------------------------------------------
// Fused aggregate, BOTH heads per edge-walk (heads share esrc; H rows and
// als pairs are adjacent -> float2 loads, shared shfl broadcasts).
// F = per-head width; one F-lane group per NODE.
// ---------------------------------------------------------------------------
template<int F, bool RELU>
__global__ __launch_bounds__(256) void gat_aggregate2(
    const int* __restrict__ rowptr, const int* __restrict__ esrc,
    const float* __restrict__ als, const float* __restrict__ ald,
    const float* __restrict__ H, const float* __restrict__ bias,
    float* __restrict__ out, float* __restrict__ denom, int N)
{
    int node = blockIdx.x * (256 / F) + (int)threadIdx.x / F;
    int lane = (int)threadIdx.x % F;
    if (node >= N) return;

    const float2 alsv = *(const float2*)(als + node * 2);
    const float2 aldv = *(const float2*)(ald + node * 2);
    const int beg = rowptr[node], end = rowptr[node + 1];

    // pass 1: per-head segment max (leaky_relu monotone)
    float mx0 = alsv.x, mx1 = alsv.y;   // self-loop
    for (int i = beg + lane; i < end; i += F) {
        float2 v = *(const float2*)(als + esrc[i] * 2);
        mx0 = fmaxf(mx0, v.x);
        mx1 = fmaxf(mx1, v.y);
    }
#pragma unroll
    for (int off = F / 2; off > 0; off >>= 1) {
        mx0 = fmaxf(mx0, __shfl_xor(mx0, off, 64));
        mx1 = fmaxf(mx1, __shfl_xor(mx1, off, 64));
    }
    const float m0 = lrelu(mx0 + aldv.x);
    const float m1 = lrelu(mx1 + aldv.y);

    const float ws0 = expf(lrelu(alsv.x + aldv.x) - m0);
    const float ws1 = expf(lrelu(alsv.y + aldv.y) - m1);
    float acc0 = ws0 * H[(size_t)node * 2 * F + lane];
    float acc1 = ws1 * H[(size_t)node * 2 * F + F + lane];
    float den0 = 0.f, den1 = 0.f;

    const int wl = (int)threadIdx.x & 63;
    const int gb = wl & ~(F - 1);

    for (int base = beg; base < end; base += F) {
        int cnt = min(F, end - base);
        int s = 0;
        float w0 = 0.f, w1 = 0.f;
        if (lane < cnt) {
            s = esrc[base + lane];
            float2 v = *(const float2*)(als + s * 2);
            w0 = expf(lrelu(v.x + aldv.x) - m0);
            w1 = expf(lrelu(v.y + aldv.y) - m1);
        }
        den0 += w0;
        den1 += w1;
        for (int i = 0; i < cnt; ++i) {
            int si = __shfl(s, gb + i, 64);
            float wi0 = __shfl(w0, gb + i, 64);
            float wi1 = __shfl(w1, gb + i, 64);
            const float* hp = H + (size_t)si * 2 * F;
            acc0 = fmaf(wi0, hp[lane], acc0);
            acc1 = fmaf(wi1, hp[F + lane], acc1);
        }
    }
#pragma unroll
    for (int off = F / 2; off > 0; off >>= 1) {
        den0 += __shfl_xor(den0, off, 64);
        den1 += __shfl_xor(den1, off, 64);
    }
    den0 += ws0;
    den1 += ws1;

    if (RELU) {
        float v0 = acc0 / (den0 + 1e-16f) + bias[lane];
        float v1 = acc1 / (den1 + 1e-16f) + bias[F + lane];
        out[(size_t)node * 2 * F + lane]     = v0 > 0.f ? v0 : 0.f;
        out[(size_t)node * 2 * F + F + lane] = v1 > 0.f ? v1 : 0.f;
    } else {
        out[(size_t)node * 2 * F + lane]     = acc0;
        out[(size_t)node * 2 * F + F + lane] = acc1;
        if (lane == 0) {
            denom[node * 2 + 0] = den0;
            denom[node * 2 + 1] = den1;
        }
    }
}

// ---------------------------------------------------------------------------
// K6b: layer 3 finalize: mean over heads + b3, softmax over 16 classes
// ---------------------------------------------------------------------------
__global__ __launch_bounds__(256) void finalize3(
    const float* __restrict__ acc, const float* __restrict__ denom,
    const float* __restrict__ b, float* __restrict__ out, int n)
{
    int node = blockIdx.x * 16 + (int)threadIdx.x / 16;
    int f = (int)threadIdx.x % 16;
    if (node >= n) return;
    float v0 = acc[(size_t)node * 32 + f]      / (denom[node * 2 + 0] + 1e-16f);
    float v1 = acc[(size_t)node * 32 + 16 + f] / (denom[node * 2 + 1] + 1e-16f);
    float v = 0.5f * (v0 + v1) + b[f];
    float mx = v;
#pragma unroll
    for (int off = 8; off > 0; off >>= 1) mx = fmaxf(mx, __shfl_xor(mx, off, 64));
    float ex = expf(v - mx);
    float sum = ex;
#pragma unroll
    for (int off = 8; off > 0; off >>= 1) sum += __shfl_xor(sum, off, 64);
    out[(size_t)node * 16 + f] = ex / sum;
}

// ---------------------------------------------------------------------------
extern "C" void kernel_launch(void* const* d_in, const int* in_sizes, int n_in,
                              void* d_out, int out_size, void* d_ws, size_t ws_size,
                              hipStream_t stream)
{
    const float* feat = (const float*)d_in[0];
    const int*   ei   = (const int*)d_in[1];
    const float* W1 = (const float*)d_in[2];
    const float* a1s = (const float*)d_in[3];
    const float* a1d = (const float*)d_in[4];
    const float* b1 = (const float*)d_in[5];
    const float* W2 = (const float*)d_in[6];
    const float* a2s = (const float*)d_in[7];
    const float* a2d = (const float*)d_in[8];
    const float* b2 = (const float*)d_in[9];
    const float* W3 = (const float*)d_in[10];
    const float* a3s = (const float*)d_in[11];
    const float* a3d = (const float*)d_in[12];
    const float* b3 = (const float*)d_in[13];

    const int N = in_sizes[0] / 64;
    const int E = in_sizes[1] / 2;
    const int* src = ei;
    const int* dst = ei + E;
    const int n2 = N * 2;
    const int nb = (N + SCAN_TILE - 1) / SCAN_TILE;

    // workspace layout
    float* bufA  = (float*)d_ws;                    // N*128 (h)
    float* bufB  = bufA + (size_t)N * 128;          // N*128 (x / acc)
    float* als   = bufB + (size_t)N * 128;          // n2
    float* ald   = als + (size_t)n2;                // n2
    float* denom = ald + (size_t)n2;                // n2
    int* deg     = (int*)(denom + (size_t)n2);      // N
    int* rowptr  = deg + N;                         // N+1
    int* cursor  = rowptr + (N + 1);                // N
    int* bsum    = cursor + N;                      // nb
    int* boff    = bsum + nb;                       // nb
    int* esorted = boff + nb;                       // E

    dim3 blk(256);
    const int gE = (E + 255) / 256;

    // --- build CSR by dst (once; shared by all 3 layers) ---
    k_zero_int<<<(N + 255) / 256, blk, 0, stream>>>(deg, N);
    k_hist<<<gE, blk, 0, stream>>>(dst, deg, E);
    k_scan1<<<nb, blk, 0, stream>>>(deg, bsum, N);
    k_scan2<<<1, blk, 0, stream>>>(bsum, boff, rowptr, nb, N);
    k_scan3<<<nb, blk, 0, stream>>>(deg, boff, rowptr, cursor, N);
    k_scatter<<<gE, blk, 0, stream>>>(src, dst, cursor, esorted, E);

    // --- layer 1 (K=64, OUT=128) ---
    gemm_logits<64, 128, 64><<<(N + 63) / 64, blk, 0, stream>>>(feat, W1, a1s, a1d, bufA, als, ald, N);
    gat_aggregate2<64, true><<<(N + 3) / 4, blk, 0, stream>>>(
        rowptr, esorted, als, ald, bufA, b1, bufB, nullptr, N);

    // --- layer 2 (K=128, OUT=128) ---
    gemm_logits<128, 128, 64><<<(N + 63) / 64, blk, 0, stream>>>(bufB, W2, a2s, a2d, bufA, als, ald, N);
    gat_aggregate2<64, true><<<(N + 3) / 4, blk, 0, stream>>>(
        rowptr, esorted, als, ald, bufA, b2, bufB, nullptr, N);

    // --- layer 3 (K=128, OUT=32, F=16) ---
    gemm_logits<128, 32, 16><<<(N + 255) / 256, blk, 0, stream>>>(bufB, W3, a3s, a3d, bufA, als, ald, N);
    gat_aggregate2<16, false><<<(N + 15) / 16, blk, 0, stream>>>(
        rowptr, esorted, als, ald, bufA, nullptr, bufB, denom, N);
    finalize3<<<(N + 15) / 16, blk, 0, stream>>>(bufB, denom, b3, (float*)d_out, N);
}